// Round 1
// baseline (534.614 us; speedup 1.0000x reference)
//
#include <hip/hip_runtime.h>
#include <hip/hip_bf16.h>
#include <math.h>

#define BATCH 4
#define SEQ   4096
#define DIM   256

typedef __attribute__((ext_vector_type(8))) short  bf16x8;
typedef __attribute__((ext_vector_type(4))) short  bf16x4;
typedef __attribute__((ext_vector_type(4))) float  f32x4;
typedef __attribute__((ext_vector_type(4))) int    i32x4;

__device__ __forceinline__ short f2bf(float f) {
    union { float f; unsigned u; } v; v.f = f;
    unsigned r = (v.u + 0x7fffu + ((v.u >> 16) & 1u)) >> 16;
    return (short)r;
}

// ---------------------------------------------------------------------------
// Projection: out[n][e] = sum_d A[n][d] * W[e][d] + bias[e]   (bf16 out)
// Block: 64 rows, 4 waves x 16 rows. K=256 in 8 steps of 32.
// ---------------------------------------------------------------------------
__global__ __launch_bounds__(256) void proj_kernel(
    const float* __restrict__ A,      // [16384][256]
    const float* __restrict__ W,      // [256][256]
    const float* __restrict__ bias,   // [256]
    unsigned short* __restrict__ out) // [16384][256] bf16
{
    __shared__ __align__(16) short Wlds[256 * 40];   // [e][32] pad->40 el (80B row)

    const int t    = threadIdx.x;
    const int wave = t >> 6, lane = t & 63;
    const int c    = lane & 15, g = lane >> 4;
    const int wrow = blockIdx.x * 64 + wave * 16;

    f32x4 acc[16];
    for (int nt = 0; nt < 16; ++nt) acc[nt] = f32x4{0.f, 0.f, 0.f, 0.f};

    for (int ks = 0; ks < 8; ++ks) {
        __syncthreads();
        // stage W[:, ks*32 .. +32) as bf16, coalesced: flat over [256][32]
        for (int i = 0; i < 8; ++i) {
            int f  = i * 1024 + t * 4;
            int r  = f >> 5, col = f & 31;
            f32x4 w4 = *(const f32x4*)&W[r * 256 + ks * 32 + col];
            bf16x4 s4;
            s4[0] = f2bf(w4[0]); s4[1] = f2bf(w4[1]);
            s4[2] = f2bf(w4[2]); s4[3] = f2bf(w4[3]);
            *(bf16x4*)&Wlds[r * 40 + col] = s4;
        }
        __syncthreads();
        // A fragment: rows = c, k = g*8..+7
        f32x4 a0 = *(const f32x4*)&A[(wrow + c) * 256 + ks * 32 + g * 8];
        f32x4 a1 = *(const f32x4*)&A[(wrow + c) * 256 + ks * 32 + g * 8 + 4];
        bf16x8 af;
        af[0] = f2bf(a0[0]); af[1] = f2bf(a0[1]); af[2] = f2bf(a0[2]); af[3] = f2bf(a0[3]);
        af[4] = f2bf(a1[0]); af[5] = f2bf(a1[1]); af[6] = f2bf(a1[2]); af[7] = f2bf(a1[3]);
        for (int nt = 0; nt < 16; ++nt) {
            bf16x8 bfr = *(const bf16x8*)&Wlds[(nt * 16 + c) * 40 + g * 8];
            acc[nt] = __builtin_amdgcn_mfma_f32_16x16x32_bf16(af, bfr, acc[nt], 0, 0, 0);
        }
    }
    // bias + store (D layout: row = 4g+j, col = c)
    for (int nt = 0; nt < 16; ++nt) {
        float bv = bias[nt * 16 + c];
        for (int j = 0; j < 4; ++j) {
            int row = wrow + g * 4 + j;
            out[row * 256 + nt * 16 + c] = (unsigned short)f2bf(acc[nt][j] + bv);
        }
    }
}

// ---------------------------------------------------------------------------
// Transpose V [b][n][d] -> Vt [b][d][n], 64x64 tiles via LDS
// ---------------------------------------------------------------------------
__global__ __launch_bounds__(256) void transpose_kernel(
    const unsigned short* __restrict__ V,   // [4][4096][256]
    unsigned short* __restrict__ Vt)        // [4][256][4096]
{
    __shared__ unsigned short lds[64 * 72];
    const int bid = blockIdx.x;          // 1024 blocks
    const int b   = bid >> 8;
    const int rem = bid & 255;
    const int n0  = (rem >> 2) * 64;
    const int d0  = (rem & 3) * 64;
    const int t   = threadIdx.x;
    const int row = t >> 2, seg = t & 3;

    *(i32x4*)&lds[row * 72 + seg * 16]     = *(const i32x4*)&V[(b * SEQ + n0 + row) * DIM + d0 + seg * 16];
    *(i32x4*)&lds[row * 72 + seg * 16 + 8] = *(const i32x4*)&V[(b * SEQ + n0 + row) * DIM + d0 + seg * 16 + 8];
    __syncthreads();

    bf16x8 v0, v1;
    for (int i = 0; i < 8; ++i) v0[i] = (short)lds[(seg * 16 + i) * 72 + row];
    for (int i = 0; i < 8; ++i) v1[i] = (short)lds[(seg * 16 + 8 + i) * 72 + row];
    unsigned short* dst = &Vt[(b * DIM + d0 + row) * SEQ + n0 + seg * 16];
    *(bf16x8*)&dst[0] = v0;
    *(bf16x8*)&dst[8] = v1;
}

// ---------------------------------------------------------------------------
// Flash attention: 256 blocks (b, qtile) with batch->XCD-pair swizzle.
// 4 waves x 16 q-rows = 64 q rows/block. KV tile = 64.
// ---------------------------------------------------------------------------
#define KROW 264   // K_lds row stride (elements): 256+8, 528B
#define VROW 72    // Vt_lds row stride: 64+8, 144B
#define PROW 72    // P_lds row stride

__global__ __launch_bounds__(256) void fa_kernel(
    const unsigned short* __restrict__ Q,   // [4][4096][256] bf16
    const unsigned short* __restrict__ K,   // [4][4096][256] bf16
    const unsigned short* __restrict__ Vt,  // [4][256][4096] bf16
    float* __restrict__ out)                // [4][4096][256] f32
{
    __shared__ __align__(16) unsigned short Klds[64 * KROW];    // 33792 B
    __shared__ __align__(16) unsigned short Vtlds[256 * VROW];  // 36864 B
    __shared__ __align__(16) unsigned short Plds[4 * 16 * PROW];//  9216 B

    const int t    = threadIdx.x;
    const int wave = t >> 6, lane = t & 63;
    const int c    = lane & 15, g = lane >> 4;
    const int bid  = blockIdx.x;
    const int xcd  = bid & 7;
    const int b    = xcd >> 1;                      // batch -> XCD pair (L2 locality)
    const int qt   = ((bid >> 3) << 1) | (xcd & 1); // 0..63
    const int q0   = qt * 64;
    const int wrow = q0 + wave * 16;

    // Q fragments: lane holds Q[wrow + c][ks*32 + g*8 .. +7]
    bf16x8 qf[8];
    const unsigned short* Qrow = &Q[((size_t)b * SEQ + wrow + c) * DIM];
    for (int ks = 0; ks < 8; ++ks)
        qf[ks] = *(const bf16x8*)&Qrow[ks * 32 + g * 8];

    f32x4 o[16];
    for (int nt = 0; nt < 16; ++nt) o[nt] = f32x4{0.f, 0.f, 0.f, 0.f};
    float m[4] = {-1e30f, -1e30f, -1e30f, -1e30f};
    float l[4] = {0.f, 0.f, 0.f, 0.f};
    const float sc_qk = 0.0625f; // 1/sqrt(256)

    for (int kv0 = 0; kv0 < SEQ; kv0 += 64) {
        __syncthreads();
        // stage K tile [64][256] (coalesced 16B/lane)
        const unsigned short* Kbase = &K[((size_t)b * SEQ + kv0) * DIM];
        for (int i = 0; i < 8; ++i) {
            int f = i * 2048 + t * 8;
            *(i32x4*)&Klds[(f >> 8) * KROW + (f & 255)] = *(const i32x4*)&Kbase[f];
        }
        // stage Vt tile [256][64]
        const unsigned short* Vbase = &Vt[(size_t)b * DIM * SEQ + kv0];
        for (int i = 0; i < 8; ++i) {
            int f = i * 2048 + t * 8;
            int vr = f >> 6, vc = f & 63;
            *(i32x4*)&Vtlds[vr * VROW + vc] = *(const i32x4*)&Vbase[(size_t)vr * SEQ + vc];
        }
        __syncthreads();

        // S = Q K^T : 4 key-tiles x 8 k-steps
        f32x4 s[4];
        for (int nt = 0; nt < 4; ++nt) s[nt] = f32x4{0.f, 0.f, 0.f, 0.f};
        for (int ks = 0; ks < 8; ++ks)
            for (int nt = 0; nt < 4; ++nt) {
                bf16x8 kf = *(const bf16x8*)&Klds[(nt * 16 + c) * KROW + ks * 32 + g * 8];
                s[nt] = __builtin_amdgcn_mfma_f32_16x16x32_bf16(qf[ks], kf, s[nt], 0, 0, 0);
            }

        // online softmax; rows handled per lane: row = 4g + j
        unsigned short* Pw = &Plds[wave * 16 * PROW];
        float scj[4];
        for (int j = 0; j < 4; ++j) {
            float s0 = s[0][j] * sc_qk, s1 = s[1][j] * sc_qk;
            float s2 = s[2][j] * sc_qk, s3 = s[3][j] * sc_qk;
            float pm = fmaxf(fmaxf(s0, s1), fmaxf(s2, s3));
            for (int d = 1; d < 16; d <<= 1) pm = fmaxf(pm, __shfl_xor(pm, d));
            float mn = fmaxf(m[j], pm);
            float rescale = __expf(m[j] - mn);
            float p0 = __expf(s0 - mn), p1 = __expf(s1 - mn);
            float p2 = __expf(s2 - mn), p3 = __expf(s3 - mn);
            float rs = p0 + p1 + p2 + p3;
            for (int d = 1; d < 16; d <<= 1) rs += __shfl_xor(rs, d);
            l[j] = l[j] * rescale + rs;
            m[j] = mn;
            scj[j] = rescale;
            int prow = g * 4 + j;
            Pw[prow * PROW + c]      = (unsigned short)f2bf(p0);
            Pw[prow * PROW + 16 + c] = (unsigned short)f2bf(p1);
            Pw[prow * PROW + 32 + c] = (unsigned short)f2bf(p2);
            Pw[prow * PROW + 48 + c] = (unsigned short)f2bf(p3);
        }
        for (int nt = 0; nt < 16; ++nt) {
            o[nt][0] *= scj[0]; o[nt][1] *= scj[1];
            o[nt][2] *= scj[2]; o[nt][3] *= scj[3];
        }

        // PV: O[16][256] += P[16][64] @ V[64][256]
        bf16x8 pa0 = *(const bf16x8*)&Pw[c * PROW + g * 8];
        bf16x8 pa1 = *(const bf16x8*)&Pw[c * PROW + 32 + g * 8];
        for (int nt = 0; nt < 16; ++nt) {
            bf16x8 vf0 = *(const bf16x8*)&Vtlds[(nt * 16 + c) * VROW + g * 8];
            o[nt] = __builtin_amdgcn_mfma_f32_16x16x32_bf16(pa0, vf0, o[nt], 0, 0, 0);
            bf16x8 vf1 = *(const bf16x8*)&Vtlds[(nt * 16 + c) * VROW + 32 + g * 8];
            o[nt] = __builtin_amdgcn_mfma_f32_16x16x32_bf16(pa1, vf1, o[nt], 0, 0, 0);
        }
    }

    // epilogue: normalize + store fp32
    float inv[4];
    for (int j = 0; j < 4; ++j) inv[j] = 1.0f / l[j];
    float* orow = &out[((size_t)b * SEQ + wrow) * DIM];
    for (int nt = 0; nt < 16; ++nt)
        for (int j = 0; j < 4; ++j)
            orow[(g * 4 + j) * DIM + nt * 16 + c] = o[nt][j] * inv[j];
}

// ---------------------------------------------------------------------------
extern "C" void kernel_launch(void* const* d_in, const int* in_sizes, int n_in,
                              void* d_out, int out_size, void* d_ws, size_t ws_size,
                              hipStream_t stream) {
    const float* x  = (const float*)d_in[0];
    const float* z  = (const float*)d_in[1];
    const float* Wq = (const float*)d_in[2];
    const float* bq = (const float*)d_in[3];
    const float* Wk = (const float*)d_in[4];
    const float* bk = (const float*)d_in[5];
    const float* Wv = (const float*)d_in[6];
    const float* bv = (const float*)d_in[7];
    float* out = (float*)d_out;

    const size_t TENS = (size_t)BATCH * SEQ * DIM; // 4,194,304 elements
    unsigned short* Qb  = (unsigned short*)d_ws;
    unsigned short* Kb  = Qb + TENS;
    unsigned short* Vb  = Kb + TENS;
    unsigned short* Vtb = Vb + TENS;

    proj_kernel<<<256, 256, 0, stream>>>(x, Wq, bq, Qb);
    proj_kernel<<<256, 256, 0, stream>>>(z, Wk, bk, Kb);
    proj_kernel<<<256, 256, 0, stream>>>(z, Wv, bv, Vb);
    transpose_kernel<<<1024, 256, 0, stream>>>(Vb, Vtb);
    fa_kernel<<<256, 256, 0, stream>>>(Qb, Kb, Vtb, out);
}

// Round 2
// 308.093 us; speedup vs baseline: 1.7352x; 1.7352x over previous
//
#include <hip/hip_runtime.h>
#include <hip/hip_bf16.h>
#include <math.h>

#define BATCH 4
#define SEQ   4096
#define DIM   256

typedef __attribute__((ext_vector_type(8))) short  bf16x8;
typedef __attribute__((ext_vector_type(4))) short  bf16x4;
typedef __attribute__((ext_vector_type(4))) float  f32x4;
typedef __attribute__((ext_vector_type(4))) int    i32x4;

__device__ __forceinline__ short f2bf(float f) {
    union { float f; unsigned u; } v; v.f = f;
    unsigned r = (v.u + 0x7fffu + ((v.u >> 16) & 1u)) >> 16;
    return (short)r;
}

// ---------------------------------------------------------------------------
// Projection: out[n][e] = sum_d A[n][d] * W[e][d] + bias[e]   (bf16 out)
// ---------------------------------------------------------------------------
__global__ __launch_bounds__(256) void proj_kernel(
    const float* __restrict__ A,      // [16384][256]
    const float* __restrict__ W,      // [256][256]
    const float* __restrict__ bias,   // [256]
    unsigned short* __restrict__ out) // [16384][256] bf16
{
    __shared__ __align__(16) short Wlds[256 * 40];

    const int t    = threadIdx.x;
    const int wave = t >> 6, lane = t & 63;
    const int c    = lane & 15, g = lane >> 4;
    const int wrow = blockIdx.x * 64 + wave * 16;

    f32x4 acc[16];
    for (int nt = 0; nt < 16; ++nt) acc[nt] = f32x4{0.f, 0.f, 0.f, 0.f};

    for (int ks = 0; ks < 8; ++ks) {
        __syncthreads();
        for (int i = 0; i < 8; ++i) {
            int f  = i * 1024 + t * 4;
            int r  = f >> 5, col = f & 31;
            f32x4 w4 = *(const f32x4*)&W[r * 256 + ks * 32 + col];
            bf16x4 s4;
            s4[0] = f2bf(w4[0]); s4[1] = f2bf(w4[1]);
            s4[2] = f2bf(w4[2]); s4[3] = f2bf(w4[3]);
            *(bf16x4*)&Wlds[r * 40 + col] = s4;
        }
        __syncthreads();
        f32x4 a0 = *(const f32x4*)&A[(wrow + c) * 256 + ks * 32 + g * 8];
        f32x4 a1 = *(const f32x4*)&A[(wrow + c) * 256 + ks * 32 + g * 8 + 4];
        bf16x8 af;
        af[0] = f2bf(a0[0]); af[1] = f2bf(a0[1]); af[2] = f2bf(a0[2]); af[3] = f2bf(a0[3]);
        af[4] = f2bf(a1[0]); af[5] = f2bf(a1[1]); af[6] = f2bf(a1[2]); af[7] = f2bf(a1[3]);
        for (int nt = 0; nt < 16; ++nt) {
            bf16x8 bfr = *(const bf16x8*)&Wlds[(nt * 16 + c) * 40 + g * 8];
            acc[nt] = __builtin_amdgcn_mfma_f32_16x16x32_bf16(af, bfr, acc[nt], 0, 0, 0);
        }
    }
    for (int nt = 0; nt < 16; ++nt) {
        float bv = bias[nt * 16 + c];
        for (int j = 0; j < 4; ++j) {
            int row = wrow + g * 4 + j;
            out[row * 256 + nt * 16 + c] = (unsigned short)f2bf(acc[nt][j] + bv);
        }
    }
}

// ---------------------------------------------------------------------------
// Transpose V [b][n][d] -> Vt [b][d][n]
// ---------------------------------------------------------------------------
__global__ __launch_bounds__(256) void transpose_kernel(
    const unsigned short* __restrict__ V,
    unsigned short* __restrict__ Vt)
{
    __shared__ unsigned short lds[64 * 72];
    const int bid = blockIdx.x;
    const int b   = bid >> 8;
    const int rem = bid & 255;
    const int n0  = (rem >> 2) * 64;
    const int d0  = (rem & 3) * 64;
    const int t   = threadIdx.x;
    const int row = t >> 2, seg = t & 3;

    *(i32x4*)&lds[row * 72 + seg * 16]     = *(const i32x4*)&V[(b * SEQ + n0 + row) * DIM + d0 + seg * 16];
    *(i32x4*)&lds[row * 72 + seg * 16 + 8] = *(const i32x4*)&V[(b * SEQ + n0 + row) * DIM + d0 + seg * 16 + 8];
    __syncthreads();

    bf16x8 v0, v1;
    for (int i = 0; i < 8; ++i) v0[i] = (short)lds[(seg * 16 + i) * 72 + row];
    for (int i = 0; i < 8; ++i) v1[i] = (short)lds[(seg * 16 + 8 + i) * 72 + row];
    unsigned short* dst = &Vt[(b * DIM + d0 + row) * SEQ + n0 + seg * 16];
    *(bf16x8*)&dst[0] = v0;
    *(bf16x8*)&dst[8] = v1;
}

// ---------------------------------------------------------------------------
// Flash attention with KV-split. Each block: 64 q rows, kv range SEQ/nsplit.
// 4 waves x 16 q-rows. KVBLK=32. LDS: K-tile (union'd with P) + Vt-tile.
// Writes l-normalized partial O (f32) + (m,l) per row per split.
// ---------------------------------------------------------------------------
#define KVB  32
#define KROW 264   // K row stride (el): 528B, shift 4 banks/row -> 2-way free
#define VROW 40    // Vt row stride (el): 80B, 16B-aligned, 2-way free
#define PROW 40    // P row stride (el): 80B, 16B-aligned

__global__ __launch_bounds__(256, 4) void fa2_kernel(
    const unsigned short* __restrict__ Q,   // [4][4096][256] bf16
    const unsigned short* __restrict__ K,   // [4][4096][256] bf16
    const unsigned short* __restrict__ Vt,  // [4][256][4096] bf16
    float* __restrict__ Opart,              // [nsplit][4][4096][256] f32 (l-normalized)
    float2* __restrict__ ml,                // [nsplit][4*4096]
    int nsplit)
{
    __shared__ __align__(16) unsigned short KP[KVB * KROW];     // 16896 B; P lives here after QK^T
    __shared__ __align__(16) unsigned short Vtlds[256 * VROW];  // 20480 B

    const int t    = threadIdx.x;
    const int wave = t >> 6, lane = t & 63;
    const int c    = lane & 15, g = lane >> 4;
    const int bid  = blockIdx.x;

    int b, sidx, qt;
    if (nsplit == 4) {
        // 1024 blocks: XCD gets 2 (b,split) combos -> KV slice 2MB L2-resident
        int xcd  = bid & 7;
        int rest = bid >> 3;           // 0..127
        qt       = rest & 63;
        int combo = xcd | ((rest >> 6) << 3);   // 0..15
        b    = combo >> 2;
        sidx = combo & 3;
    } else {
        int xcd = bid & 7;
        b    = xcd >> 1;
        qt   = ((bid >> 3) << 1) | (xcd & 1);
        sidx = 0;
    }
    const int kvlen   = SEQ / nsplit;
    const int kv0base = sidx * kvlen;
    const int q0   = qt * 64;
    const int wrow = q0 + wave * 16;

    // Q fragments
    bf16x8 qf[8];
    const unsigned short* Qrow = &Q[((size_t)b * SEQ + wrow + c) * DIM];
    for (int ks = 0; ks < 8; ++ks)
        qf[ks] = *(const bf16x8*)&Qrow[ks * 32 + g * 8];

    f32x4 o[16];
    for (int nt = 0; nt < 16; ++nt) o[nt] = f32x4{0.f, 0.f, 0.f, 0.f};
    float m[4] = {-1e30f, -1e30f, -1e30f, -1e30f};
    float l[4] = {0.f, 0.f, 0.f, 0.f};
    const float sc_qk = 0.0625f; // 1/sqrt(256)

    const unsigned short* Kbase = &K[(size_t)b * SEQ * DIM];
    const unsigned short* Vbase = &Vt[(size_t)b * DIM * SEQ];
    unsigned short* Pw = &KP[wave * 16 * PROW];  // per-wave P region inside K tile

    const int ntiles = kvlen / KVB;
    for (int kt = 0; kt < ntiles; ++kt) {
        const int kv0 = kv0base + kt * KVB;
        __syncthreads();   // (A) prev tile's PV (Vt reads, P reads) complete
        // stage K tile [32][256] -> KP (coalesced 16B/lane, conflict-free)
        for (int i = 0; i < 4; ++i) {
            int f = i * 2048 + t * 8;
            *(i32x4*)&KP[(f >> 8) * KROW + (f & 255)] =
                *(const i32x4*)&Kbase[(size_t)kv0 * DIM + f];
        }
        // stage Vt tile [256][32] (80B rows: write banks spread evenly)
        for (int i = 0; i < 4; ++i) {
            int f = i * 2048 + t * 8;
            int vr = f >> 5, vc = f & 31;
            *(i32x4*)&Vtlds[vr * VROW + vc] =
                *(const i32x4*)&Vbase[(size_t)vr * SEQ + kv0 + vc];
        }
        __syncthreads();   // (B) staging visible

        // S = Q K^T : 2 key-tiles x 8 k-steps
        f32x4 s0 = f32x4{0.f, 0.f, 0.f, 0.f};
        f32x4 s1 = f32x4{0.f, 0.f, 0.f, 0.f};
        for (int ks = 0; ks < 8; ++ks) {
            bf16x8 kf0 = *(const bf16x8*)&KP[(c) * KROW + ks * 32 + g * 8];
            s0 = __builtin_amdgcn_mfma_f32_16x16x32_bf16(qf[ks], kf0, s0, 0, 0, 0);
            bf16x8 kf1 = *(const bf16x8*)&KP[(16 + c) * KROW + ks * 32 + g * 8];
            s1 = __builtin_amdgcn_mfma_f32_16x16x32_bf16(qf[ks], kf1, s1, 0, 0, 0);
        }

        // online softmax (values into regs first; K still being read by others)
        float scj[4], p0v[4], p1v[4];
        for (int j = 0; j < 4; ++j) {
            float sm0 = s0[j] * sc_qk, sm1 = s1[j] * sc_qk;
            float pm = fmaxf(sm0, sm1);
            for (int d = 1; d < 16; d <<= 1) pm = fmaxf(pm, __shfl_xor(pm, d));
            float mn = fmaxf(m[j], pm);
            float rescale = __expf(m[j] - mn);
            float p0 = __expf(sm0 - mn), p1 = __expf(sm1 - mn);
            float rs = p0 + p1;
            for (int d = 1; d < 16; d <<= 1) rs += __shfl_xor(rs, d);
            l[j] = l[j] * rescale + rs;
            m[j] = mn;
            scj[j] = rescale;
            p0v[j] = p0; p1v[j] = p1;
        }
        __syncthreads();   // (C) all waves done reading K -> safe to write P over it

        for (int j = 0; j < 4; ++j) {
            int prow = g * 4 + j;
            Pw[prow * PROW + c]      = (unsigned short)f2bf(p0v[j]);
            Pw[prow * PROW + 16 + c] = (unsigned short)f2bf(p1v[j]);
        }
        for (int nt = 0; nt < 16; ++nt) {
            o[nt][0] *= scj[0]; o[nt][1] *= scj[1];
            o[nt][2] *= scj[2]; o[nt][3] *= scj[3];
        }

        // PV: O[16][256] += P[16][32] @ V[32][256]
        bf16x8 pa = *(const bf16x8*)&Pw[c * PROW + g * 8];
        for (int nt = 0; nt < 16; ++nt) {
            bf16x8 vf = *(const bf16x8*)&Vtlds[(nt * 16 + c) * VROW + g * 8];
            o[nt] = __builtin_amdgcn_mfma_f32_16x16x32_bf16(pa, vf, o[nt], 0, 0, 0);
        }
    }

    // epilogue: l-normalized partial + (m,l)
    float inv[4];
    for (int j = 0; j < 4; ++j) inv[j] = 1.0f / l[j];
    const size_t obase = ((size_t)sidx * BATCH * SEQ + (size_t)b * SEQ + wrow) * DIM;
    for (int nt = 0; nt < 16; ++nt)
        for (int j = 0; j < 4; ++j)
            Opart[obase + (size_t)(g * 4 + j) * DIM + nt * 16 + c] = o[nt][j] * inv[j];
    if (c == 0) {
        for (int j = 0; j < 4; ++j)
            ml[(size_t)sidx * BATCH * SEQ + (size_t)b * SEQ + wrow + g * 4 + j] =
                make_float2(m[j], l[j]);
    }
}

// ---------------------------------------------------------------------------
// Combine 4 KV-split partials: O = sum_s w_s * O_s, w_s = l_s exp(m_s - M)/L
// ---------------------------------------------------------------------------
__global__ __launch_bounds__(256) void combine_kernel(
    const float* __restrict__ Opart, const float2* __restrict__ ml,
    float* __restrict__ out)
{
    const int t = threadIdx.x;
    const size_t row = (size_t)blockIdx.x * 4 + (t >> 6);  // 0..16383
    const int lane = t & 63;

    float2 e[4];
    float M = -1e30f;
    for (int s = 0; s < 4; ++s) {
        e[s] = ml[(size_t)s * BATCH * SEQ + row];
        M = fmaxf(M, e[s].x);
    }
    float w[4], L = 0.f;
    for (int s = 0; s < 4; ++s) { w[s] = e[s].y * __expf(e[s].x - M); L += w[s]; }
    float invL = 1.0f / L;

    f32x4 acc = f32x4{0.f, 0.f, 0.f, 0.f};
    for (int s = 0; s < 4; ++s) {
        f32x4 v = *(const f32x4*)&Opart[((size_t)s * BATCH * SEQ + row) * DIM + lane * 4];
        float ws = w[s] * invL;
        acc[0] += ws * v[0]; acc[1] += ws * v[1];
        acc[2] += ws * v[2]; acc[3] += ws * v[3];
    }
    *(f32x4*)&out[row * DIM + lane * 4] = acc;
}

// ---------------------------------------------------------------------------
extern "C" void kernel_launch(void* const* d_in, const int* in_sizes, int n_in,
                              void* d_out, int out_size, void* d_ws, size_t ws_size,
                              hipStream_t stream) {
    const float* x  = (const float*)d_in[0];
    const float* z  = (const float*)d_in[1];
    const float* Wq = (const float*)d_in[2];
    const float* bq = (const float*)d_in[3];
    const float* Wk = (const float*)d_in[4];
    const float* bk = (const float*)d_in[5];
    const float* Wv = (const float*)d_in[6];
    const float* bv = (const float*)d_in[7];
    float* out = (float*)d_out;

    const size_t TENS = (size_t)BATCH * SEQ * DIM; // 4,194,304 elements
    unsigned short* Qb  = (unsigned short*)d_ws;
    unsigned short* Kb  = Qb + TENS;
    unsigned short* Vb  = Kb + TENS;
    unsigned short* Vtb = Vb + TENS;

    const size_t base_bytes = 4 * TENS * sizeof(unsigned short);       // 32 MB
    const size_t need4 = base_bytes + 4 * TENS * sizeof(float)         // 64 MB
                       + 4 * (size_t)BATCH * SEQ * sizeof(float2);     // 0.5 MB
    const int nsplit = (ws_size >= need4) ? 4 : 1;

    proj_kernel<<<256, 256, 0, stream>>>(x, Wq, bq, Qb);
    proj_kernel<<<256, 256, 0, stream>>>(z, Wk, bk, Kb);
    proj_kernel<<<256, 256, 0, stream>>>(z, Wv, bv, Vb);
    transpose_kernel<<<1024, 256, 0, stream>>>(Vb, Vtb);

    if (nsplit == 4) {
        float*  Op = (float*)((char*)d_ws + base_bytes);
        float2* mlb = (float2*)((char*)d_ws + base_bytes + 4 * TENS * sizeof(float));
        fa2_kernel<<<1024, 256, 0, stream>>>(Qb, Kb, Vtb, Op, mlb, 4);
        combine_kernel<<<4096, 256, 0, stream>>>(Op, mlb, out);
    } else {
        // fallback: partials ARE the output (already l-normalized); ml into dead Vb
        fa2_kernel<<<256, 256, 0, stream>>>(Qb, Kb, Vtb, out, (float2*)Vb, 1);
    }
}

// Round 3
// 214.302 us; speedup vs baseline: 2.4947x; 1.4377x over previous
//
#include <hip/hip_runtime.h>
#include <hip/hip_bf16.h>
#include <math.h>

#define BATCH 4
#define SEQ   4096
#define DIM   256

typedef __attribute__((ext_vector_type(8))) short  bf16x8;
typedef __attribute__((ext_vector_type(4))) short  bf16x4;
typedef __attribute__((ext_vector_type(4))) float  f32x4;
typedef __attribute__((ext_vector_type(4))) int    i32x4;

__device__ __forceinline__ short f2bf(float f) {
    union { float f; unsigned u; } v; v.f = f;
    unsigned r = (v.u + 0x7fffu + ((v.u >> 16) & 1u)) >> 16;
    return (short)r;
}

// ---------------------------------------------------------------------------
// Projection: out[n][e] = sum_d A[n][d] * W[e][d] + bias[e]   (bf16 out)
// Reg-prefetch double-buffered W staging. TRANS=true stores out^T ([e][n]).
// ---------------------------------------------------------------------------
template<bool TRANS>
__global__ __launch_bounds__(256) void proj_kernel(
    const float* __restrict__ A,      // [16384][256]
    const float* __restrict__ W,      // [256][256]
    const float* __restrict__ bias,   // [256]
    unsigned short* __restrict__ out) // [16384][256] bf16  (or [b][256][4096] if TRANS)
{
    __shared__ __align__(16) short Wlds[256 * 40];

    const int t    = threadIdx.x;
    const int wave = t >> 6, lane = t & 63;
    const int c    = lane & 15, g = lane >> 4;
    const int wrow = blockIdx.x * 64 + wave * 16;

    f32x4 acc[16];
    for (int nt = 0; nt < 16; ++nt) acc[nt] = f32x4{0.f, 0.f, 0.f, 0.f};

    // prefetch ks=0
    f32x4 wpf[8];
    for (int i = 0; i < 8; ++i) {
        int f = i * 1024 + t * 4;
        int r = f >> 5, col = f & 31;
        wpf[i] = *(const f32x4*)&W[r * 256 + col];
    }
    f32x4 a0 = *(const f32x4*)&A[(wrow + c) * 256 + g * 8];
    f32x4 a1 = *(const f32x4*)&A[(wrow + c) * 256 + g * 8 + 4];

    for (int ks = 0; ks < 8; ++ks) {
        __syncthreads();
        for (int i = 0; i < 8; ++i) {
            int f = i * 1024 + t * 4;
            int r = f >> 5, col = f & 31;
            bf16x4 s4;
            s4[0] = f2bf(wpf[i][0]); s4[1] = f2bf(wpf[i][1]);
            s4[2] = f2bf(wpf[i][2]); s4[3] = f2bf(wpf[i][3]);
            *(bf16x4*)&Wlds[r * 40 + col] = s4;
        }
        __syncthreads();
        bf16x8 af;
        af[0] = f2bf(a0[0]); af[1] = f2bf(a0[1]); af[2] = f2bf(a0[2]); af[3] = f2bf(a0[3]);
        af[4] = f2bf(a1[0]); af[5] = f2bf(a1[1]); af[6] = f2bf(a1[2]); af[7] = f2bf(a1[3]);
        if (ks < 7) {
            for (int i = 0; i < 8; ++i) {
                int f = i * 1024 + t * 4;
                int r = f >> 5, col = f & 31;
                wpf[i] = *(const f32x4*)&W[r * 256 + (ks + 1) * 32 + col];
            }
            a0 = *(const f32x4*)&A[(wrow + c) * 256 + (ks + 1) * 32 + g * 8];
            a1 = *(const f32x4*)&A[(wrow + c) * 256 + (ks + 1) * 32 + g * 8 + 4];
        }
        __builtin_amdgcn_s_setprio(1);
        for (int nt = 0; nt < 16; ++nt) {
            bf16x8 bfr = *(const bf16x8*)&Wlds[(nt * 16 + c) * 40 + g * 8];
            acc[nt] = __builtin_amdgcn_mfma_f32_16x16x32_bf16(af, bfr, acc[nt], 0, 0, 0);
        }
        __builtin_amdgcn_s_setprio(0);
    }

    if constexpr (TRANS) {
        // out is [b][256][4096]; rows in a block share the same b
        const int nb = wrow >> 12, n0 = wrow & 4095;
        for (int nt = 0; nt < 16; ++nt) {
            float bv = bias[nt * 16 + c];
            bf16x4 s4;
            s4[0] = f2bf(acc[nt][0] + bv); s4[1] = f2bf(acc[nt][1] + bv);
            s4[2] = f2bf(acc[nt][2] + bv); s4[3] = f2bf(acc[nt][3] + bv);
            *(bf16x4*)&out[((size_t)nb * DIM + nt * 16 + c) * SEQ + n0 + g * 4] = s4;
        }
    } else {
        for (int nt = 0; nt < 16; ++nt) {
            float bv = bias[nt * 16 + c];
            for (int j = 0; j < 4; ++j)
                out[(size_t)(wrow + g * 4 + j) * 256 + nt * 16 + c] =
                    (unsigned short)f2bf(acc[nt][j] + bv);
        }
    }
}

// ---------------------------------------------------------------------------
// Flash attention, KV-split=3. 4 waves x 16 q-rows, KVB=32.
// Reg-prefetch K/V staging (2 barriers/tile), wave-private P buffer.
// ---------------------------------------------------------------------------
#define KVB   32
#define KROW  264   // 528B rows: 4-bank shift/row, reads conflict-free
#define VROW  40    // 80B rows, 16B-aligned
#define PROWB 32    // 64B rows (wave-private, single b128 read/tile)

__global__ __launch_bounds__(256, 3) void fa2_kernel(
    const unsigned short* __restrict__ Q,   // [4][4096][256] bf16
    const unsigned short* __restrict__ K,   // [4][4096][256] bf16
    const unsigned short* __restrict__ Vt,  // [4][256][4096] bf16
    float* __restrict__ Opart,              // [nsplit][4][4096][256] f32 (l-normalized)
    float2* __restrict__ ml,                // [nsplit][4*4096]
    int nsplit)
{
    __shared__ __align__(16) unsigned short KP[KVB * KROW];     // 16896 B
    __shared__ __align__(16) unsigned short Vtlds[256 * VROW];  // 20480 B
    __shared__ __align__(16) unsigned short Plds[4 * 16 * PROWB]; // 4096 B

    const int t    = threadIdx.x;
    const int wave = t >> 6, lane = t & 63;
    const int c    = lane & 15, g = lane >> 4;
    const int bid  = blockIdx.x;

    int b, sidx, qt;
    if (nsplit == 3) {
        // 768 blocks = 3/CU exactly; per-XCD contiguous combo+qt for L2 locality
        int xcd  = bid & 7;
        int rest = bid >> 3;            // 0..95
        int g2   = xcd * 96 + rest;     // 0..767
        int combo = g2 >> 6;            // 0..11
        qt   = g2 & 63;
        b    = combo & 3;
        sidx = combo >> 2;              // 0..2
    } else {
        int xcd = bid & 7;
        b    = xcd >> 1;
        qt   = ((bid >> 3) << 1) | (xcd & 1);
        sidx = 0;
    }
    int ts, te;
    if (nsplit == 3) { ts = (sidx * 128) / 3; te = ((sidx + 1) * 128) / 3; }
    else             { ts = 0; te = 128; }

    const int q0   = qt * 64;
    const int wrow = q0 + wave * 16;

    // Q fragments (held in regs for the whole kernel)
    bf16x8 qf[8];
    const unsigned short* Qrow = &Q[((size_t)b * SEQ + wrow + c) * DIM];
    for (int ks = 0; ks < 8; ++ks)
        qf[ks] = *(const bf16x8*)&Qrow[ks * 32 + g * 8];

    f32x4 o[16];
    for (int nt = 0; nt < 16; ++nt) o[nt] = f32x4{0.f, 0.f, 0.f, 0.f};
    float m[4] = {-1e30f, -1e30f, -1e30f, -1e30f};
    float l[4] = {0.f, 0.f, 0.f, 0.f};
    const float sc_qk = 0.0625f; // 1/sqrt(256)

    const unsigned short* Kbase = &K[(size_t)b * SEQ * DIM];
    const unsigned short* Vbase = &Vt[(size_t)b * DIM * SEQ];
    unsigned short* Pw = &Plds[wave * 16 * PROWB];

    // prologue: prefetch first tile into regs
    i32x4 kpf[4], vpf[4];
    {
        int kv0 = ts * KVB;
        for (int i = 0; i < 4; ++i) {
            int f = i * 2048 + t * 8;
            kpf[i] = *(const i32x4*)&Kbase[(size_t)kv0 * DIM + f];
            int vr = f >> 5, vc = f & 31;
            vpf[i] = *(const i32x4*)&Vbase[(size_t)vr * SEQ + kv0 + vc];
        }
    }

    for (int kt = ts; kt < te; ++kt) {
        __syncthreads();   // (A) all waves done reading KP/Vtlds from prev tile
        for (int i = 0; i < 4; ++i) {
            int f = i * 2048 + t * 8;
            *(i32x4*)&KP[(f >> 8) * KROW + (f & 255)] = kpf[i];
            int vr = f >> 5, vc = f & 31;
            *(i32x4*)&Vtlds[vr * VROW + vc] = vpf[i];
        }
        __syncthreads();   // (B) staging visible

        // issue next tile's loads (consumed at next (A) -> latency hidden)
        if (kt + 1 < te) {
            int kv0n = (kt + 1) * KVB;
            for (int i = 0; i < 4; ++i) {
                int f = i * 2048 + t * 8;
                kpf[i] = *(const i32x4*)&Kbase[(size_t)kv0n * DIM + f];
                int vr = f >> 5, vc = f & 31;
                vpf[i] = *(const i32x4*)&Vbase[(size_t)vr * SEQ + kv0n + vc];
            }
        }

        // S = Q K^T : 2 key-tiles x 8 k-steps
        f32x4 s0 = f32x4{0.f, 0.f, 0.f, 0.f};
        f32x4 s1 = f32x4{0.f, 0.f, 0.f, 0.f};
        __builtin_amdgcn_s_setprio(1);
        for (int ks = 0; ks < 8; ++ks) {
            bf16x8 kf0 = *(const bf16x8*)&KP[c * KROW + ks * 32 + g * 8];
            s0 = __builtin_amdgcn_mfma_f32_16x16x32_bf16(qf[ks], kf0, s0, 0, 0, 0);
            bf16x8 kf1 = *(const bf16x8*)&KP[(16 + c) * KROW + ks * 32 + g * 8];
            s1 = __builtin_amdgcn_mfma_f32_16x16x32_bf16(qf[ks], kf1, s1, 0, 0, 0);
        }
        __builtin_amdgcn_s_setprio(0);

        // online softmax; q-row = 4g+j; P -> wave-private LDS (no barrier)
        float scj[4];
        for (int j = 0; j < 4; ++j) {
            float sm0 = s0[j] * sc_qk, sm1 = s1[j] * sc_qk;
            float pm = fmaxf(sm0, sm1);
            for (int d = 1; d < 16; d <<= 1) pm = fmaxf(pm, __shfl_xor(pm, d));
            float mn = fmaxf(m[j], pm);
            float rescale = __expf(m[j] - mn);
            float p0 = __expf(sm0 - mn), p1 = __expf(sm1 - mn);
            float rs = p0 + p1;
            for (int d = 1; d < 16; d <<= 1) rs += __shfl_xor(rs, d);
            l[j] = l[j] * rescale + rs;
            m[j] = mn;
            scj[j] = rescale;
            int prow = g * 4 + j;
            Pw[prow * PROWB + c]      = (unsigned short)f2bf(p0);
            Pw[prow * PROWB + 16 + c] = (unsigned short)f2bf(p1);
        }
        for (int nt = 0; nt < 16; ++nt) {
            o[nt][0] *= scj[0]; o[nt][1] *= scj[1];
            o[nt][2] *= scj[2]; o[nt][3] *= scj[3];
        }

        // PV: O[16][256] += P[16][32] @ V[32][256]
        bf16x8 pa = *(const bf16x8*)&Pw[c * PROWB + g * 8];
        __builtin_amdgcn_s_setprio(1);
        for (int nt = 0; nt < 16; ++nt) {
            bf16x8 vf = *(const bf16x8*)&Vtlds[(nt * 16 + c) * VROW + g * 8];
            o[nt] = __builtin_amdgcn_mfma_f32_16x16x32_bf16(pa, vf, o[nt], 0, 0, 0);
        }
        __builtin_amdgcn_s_setprio(0);
    }

    // epilogue: l-normalized partial + (m,l)
    float inv[4];
    for (int j = 0; j < 4; ++j) inv[j] = 1.0f / l[j];
    const size_t obase = ((size_t)sidx * BATCH * SEQ + (size_t)b * SEQ + wrow) * DIM;
    for (int nt = 0; nt < 16; ++nt)
        for (int j = 0; j < 4; ++j)
            Opart[obase + (size_t)(g * 4 + j) * DIM + nt * 16 + c] = o[nt][j] * inv[j];
    if (c == 0) {
        for (int j = 0; j < 4; ++j)
            ml[(size_t)sidx * BATCH * SEQ + (size_t)b * SEQ + wrow + g * 4 + j] =
                make_float2(m[j], l[j]);
    }
}

// ---------------------------------------------------------------------------
// Combine 3 KV-split partials
// ---------------------------------------------------------------------------
__global__ __launch_bounds__(256) void combine_kernel(
    const float* __restrict__ Opart, const float2* __restrict__ ml,
    float* __restrict__ out)
{
    const int t = threadIdx.x;
    const size_t row = (size_t)blockIdx.x * 4 + (t >> 6);
    const int lane = t & 63;

    float2 e[3];
    float M = -1e30f;
    for (int s = 0; s < 3; ++s) {
        e[s] = ml[(size_t)s * BATCH * SEQ + row];
        M = fmaxf(M, e[s].x);
    }
    float w[3], L = 0.f;
    for (int s = 0; s < 3; ++s) { w[s] = e[s].y * __expf(e[s].x - M); L += w[s]; }
    float invL = 1.0f / L;

    f32x4 acc = f32x4{0.f, 0.f, 0.f, 0.f};
    for (int s = 0; s < 3; ++s) {
        f32x4 v = *(const f32x4*)&Opart[((size_t)s * BATCH * SEQ + row) * DIM + lane * 4];
        float ws = w[s] * invL;
        acc[0] += ws * v[0]; acc[1] += ws * v[1];
        acc[2] += ws * v[2]; acc[3] += ws * v[3];
    }
    *(f32x4*)&out[row * DIM + lane * 4] = acc;
}

// ---------------------------------------------------------------------------
extern "C" void kernel_launch(void* const* d_in, const int* in_sizes, int n_in,
                              void* d_out, int out_size, void* d_ws, size_t ws_size,
                              hipStream_t stream) {
    const float* x  = (const float*)d_in[0];
    const float* z  = (const float*)d_in[1];
    const float* Wq = (const float*)d_in[2];
    const float* bq = (const float*)d_in[3];
    const float* Wk = (const float*)d_in[4];
    const float* bk = (const float*)d_in[5];
    const float* Wv = (const float*)d_in[6];
    const float* bv = (const float*)d_in[7];
    float* out = (float*)d_out;

    const size_t TENS = (size_t)BATCH * SEQ * DIM; // 4,194,304 elements
    unsigned short* Qb  = (unsigned short*)d_ws;
    unsigned short* Kb  = Qb + TENS;
    unsigned short* Vtb = Kb + TENS;

    const size_t base_bytes = 3 * TENS * sizeof(unsigned short);       // 24 MB
    const size_t need3 = base_bytes + 3 * TENS * sizeof(float)         // 48 MB
                       + 3 * (size_t)BATCH * SEQ * sizeof(float2);     // 0.4 MB
    const int nsplit = (ws_size >= need3) ? 3 : 1;

    proj_kernel<false><<<256, 256, 0, stream>>>(x, Wq, bq, Qb);
    proj_kernel<false><<<256, 256, 0, stream>>>(z, Wk, bk, Kb);
    proj_kernel<true ><<<256, 256, 0, stream>>>(z, Wv, bv, Vtb);

    if (nsplit == 3) {
        float*  Op  = (float*)((char*)d_ws + base_bytes);
        float2* mlb = (float2*)((char*)d_ws + base_bytes + 3 * TENS * sizeof(float));
        fa2_kernel<<<768, 256, 0, stream>>>(Qb, Kb, Vtb, Op, mlb, 3);
        combine_kernel<<<4096, 256, 0, stream>>>(Op, mlb, out);
    } else {
        float2* mlb = (float2*)((char*)d_ws + base_bytes);
        fa2_kernel<<<256, 256, 0, stream>>>(Qb, Kb, Vtb, out, mlb, 1);
    }
}

// Round 4
// 196.114 us; speedup vs baseline: 2.7260x; 1.0927x over previous
//
#include <hip/hip_runtime.h>
#include <hip/hip_bf16.h>
#include <math.h>

#define BATCH 4
#define SEQ   4096
#define DIM   256
#define AS1 __attribute__((address_space(1)))
#define AS3 __attribute__((address_space(3)))

typedef __attribute__((ext_vector_type(8))) short  bf16x8;
typedef __attribute__((ext_vector_type(4))) short  bf16x4;
typedef __attribute__((ext_vector_type(4))) float  f32x4;
typedef __attribute__((ext_vector_type(4))) int    i32x4;

__device__ __forceinline__ short f2bf(float f) {
    union { float f; unsigned u; } v; v.f = f;
    unsigned r = (v.u + 0x7fffu + ((v.u >> 16) & 1u)) >> 16;
    return (short)r;
}

__device__ __forceinline__ void gload_lds16(const void* g, void* l) {
    __builtin_amdgcn_global_load_lds((const AS1 void*)g, (AS3 void*)l, 16, 0, 0);
}

// ---------------------------------------------------------------------------
// Projection: out[n][e] = sum_d A[n][d] * W[e][d] + bias[e]   (bf16 out)
// TRANS=true stores out^T per batch ([b][256][4096]).
// ---------------------------------------------------------------------------
template<bool TRANS>
__global__ __launch_bounds__(256) void proj_kernel(
    const float* __restrict__ A,
    const float* __restrict__ W,
    const float* __restrict__ bias,
    unsigned short* __restrict__ out)
{
    __shared__ __align__(16) short Wlds[256 * 40];

    const int t    = threadIdx.x;
    const int wave = t >> 6, lane = t & 63;
    const int c    = lane & 15, g = lane >> 4;
    const int wrow = blockIdx.x * 64 + wave * 16;

    f32x4 acc[16];
    for (int nt = 0; nt < 16; ++nt) acc[nt] = f32x4{0.f, 0.f, 0.f, 0.f};

    f32x4 wpf[8];
    for (int i = 0; i < 8; ++i) {
        int f = i * 1024 + t * 4;
        wpf[i] = *(const f32x4*)&W[(f >> 5) * 256 + (f & 31)];
    }
    f32x4 a0 = *(const f32x4*)&A[(wrow + c) * 256 + g * 8];
    f32x4 a1 = *(const f32x4*)&A[(wrow + c) * 256 + g * 8 + 4];

    for (int ks = 0; ks < 8; ++ks) {
        __syncthreads();
        for (int i = 0; i < 8; ++i) {
            int f = i * 1024 + t * 4;
            bf16x4 s4;
            s4[0] = f2bf(wpf[i][0]); s4[1] = f2bf(wpf[i][1]);
            s4[2] = f2bf(wpf[i][2]); s4[3] = f2bf(wpf[i][3]);
            *(bf16x4*)&Wlds[(f >> 5) * 40 + (f & 31)] = s4;
        }
        __syncthreads();
        bf16x8 af;
        af[0] = f2bf(a0[0]); af[1] = f2bf(a0[1]); af[2] = f2bf(a0[2]); af[3] = f2bf(a0[3]);
        af[4] = f2bf(a1[0]); af[5] = f2bf(a1[1]); af[6] = f2bf(a1[2]); af[7] = f2bf(a1[3]);
        if (ks < 7) {
            for (int i = 0; i < 8; ++i) {
                int f = i * 1024 + t * 4;
                wpf[i] = *(const f32x4*)&W[(f >> 5) * 256 + (ks + 1) * 32 + (f & 31)];
            }
            a0 = *(const f32x4*)&A[(wrow + c) * 256 + (ks + 1) * 32 + g * 8];
            a1 = *(const f32x4*)&A[(wrow + c) * 256 + (ks + 1) * 32 + g * 8 + 4];
        }
        __builtin_amdgcn_s_setprio(1);
        for (int nt = 0; nt < 16; ++nt) {
            bf16x8 bfr = *(const bf16x8*)&Wlds[(nt * 16 + c) * 40 + g * 8];
            acc[nt] = __builtin_amdgcn_mfma_f32_16x16x32_bf16(af, bfr, acc[nt], 0, 0, 0);
        }
        __builtin_amdgcn_s_setprio(0);
    }

    if constexpr (TRANS) {
        const int nb = wrow >> 12, n0 = wrow & 4095;
        for (int nt = 0; nt < 16; ++nt) {
            float bv = bias[nt * 16 + c];
            bf16x4 s4;
            s4[0] = f2bf(acc[nt][0] + bv); s4[1] = f2bf(acc[nt][1] + bv);
            s4[2] = f2bf(acc[nt][2] + bv); s4[3] = f2bf(acc[nt][3] + bv);
            *(bf16x4*)&out[((size_t)nb * DIM + nt * 16 + c) * SEQ + n0 + g * 4] = s4;
        }
    } else {
        for (int nt = 0; nt < 16; ++nt) {
            float bv = bias[nt * 16 + c];
            for (int j = 0; j < 4; ++j)
                out[(size_t)(wrow + g * 4 + j) * 256 + nt * 16 + c] =
                    (unsigned short)f2bf(acc[nt][j] + bv);
        }
    }
}

// ---------------------------------------------------------------------------
// Flash attention. 8 waves x 16 q-rows = 128 q-rows/block. KVB=32.
// global_load_lds staging (pre-swizzled source, linear LDS dest),
// double-buffered K/V LDS, counted vmcnt, defer-max softmax.
// K swizzle: el = row*256 + (col ^ ((row&7)<<3))        [512B rows]
// V swizzle: el = row*32  + (col ^ (((row&3)^((row>>2)&3))<<3))  [64B rows]
// ---------------------------------------------------------------------------
#define KVB  32
#define PROW 40

__global__ __launch_bounds__(512, 4) void fa2_kernel(
    const unsigned short* __restrict__ Q,   // [4][4096][256] bf16
    const unsigned short* __restrict__ K,   // [4][4096][256] bf16
    const unsigned short* __restrict__ Vt,  // [4][256][4096] bf16
    float* __restrict__ Opart,              // [nsplit][4][4096][256] f32 (l-normalized)
    float2* __restrict__ ml,                // [nsplit][4*4096]
    int nsplit)
{
    __shared__ __align__(16) unsigned short Klds[2][KVB * 256];   // 2 x 16 KB
    __shared__ __align__(16) unsigned short Vlds[2][256 * KVB];   // 2 x 16 KB
    __shared__ __align__(16) unsigned short Plds[8 * 16 * PROW];  // 10240 B

    const int t = threadIdx.x;
    const int w = t >> 6, lane = t & 63;
    const int c = lane & 15, g = lane >> 4;

    int b, sidx, qt;
    if (nsplit == 4) {
        int xcd  = blockIdx.x & 7;
        int rest = blockIdx.x >> 3;            // 0..63
        int combo = (xcd << 1) | (rest >> 5);  // 0..15 ; 2 combos per XCD
        qt   = rest & 31;
        b    = combo >> 2;
        sidx = combo & 3;
    } else {
        qt   = blockIdx.x & 31;
        b    = blockIdx.x >> 5;
        sidx = 0;
    }
    const int ts = (sidx * 128) / nsplit;
    const int te = ((sidx + 1) * 128) / nsplit;

    const int wrow = qt * 128 + w * 16;

    // Q fragments (regs for whole kernel)
    bf16x8 qf[8];
    const unsigned short* Qrow = &Q[((size_t)b * SEQ + wrow + c) * DIM];
    for (int ks = 0; ks < 8; ++ks)
        qf[ks] = *(const bf16x8*)&Qrow[ks * 32 + g * 8];

    f32x4 o[16];
    for (int nt = 0; nt < 16; ++nt) o[nt] = f32x4{0.f, 0.f, 0.f, 0.f};
    float m[4]     = {-1e30f, -1e30f, -1e30f, -1e30f};
    float llane[4] = {0.f, 0.f, 0.f, 0.f};
    const float sc_qk = 0.0625f; // 1/sqrt(256)

    const char* Kb_ = (const char*)&K[(size_t)b * SEQ * DIM];
    const char* Vb_ = (const char*)&Vt[(size_t)b * DIM * SEQ];

    // Staging geometry: 16 x 1KB calls per tile for K and for V; wave w does
    // calls 2w,2w+1 of each. LDS dest is linear (base + lane*16B); the SOURCE
    // address carries the inverse swizzle (rule: swizzle both sides via source).
    const int krow0 = 4 * w + (lane >> 5);
    const int krow1 = krow0 + 2;
    const int koff0 = krow0 * 512 + (((lane & 31) ^ (krow0 & 7)) << 4);
    const int koff1 = krow1 * 512 + (((lane & 31) ^ (krow1 & 7)) << 4);
    const int vrow0 = 32 * w + (lane >> 2);
    const int vrow1 = vrow0 + 16;
    const int vsw0 = ((vrow0 & 3) ^ ((vrow0 >> 2) & 3));
    const int vsw1 = ((vrow1 & 3) ^ ((vrow1 >> 2) & 3));
    const int voff0 = vrow0 * (SEQ * 2) + (((lane & 3) ^ vsw0) << 4);
    const int voff1 = vrow1 * (SEQ * 2) + (((lane & 3) ^ vsw1) << 4);

    #define STAGE(kt_, buf_) do {                                              \
        const int kb_ = (kt_) * (KVB * DIM * 2);                               \
        const int vb_ = (kt_) * (KVB * 2);                                     \
        gload_lds16(Kb_ + kb_ + koff0, &Klds[buf_][(2 * w)     * 512]);        \
        gload_lds16(Kb_ + kb_ + koff1, &Klds[buf_][(2 * w + 1) * 512]);        \
        gload_lds16(Vb_ + vb_ + voff0, &Vlds[buf_][(2 * w)     * 512]);        \
        gload_lds16(Vb_ + vb_ + voff1, &Vlds[buf_][(2 * w + 1) * 512]);        \
    } while (0)

    STAGE(ts, 0);
    int buf = 0;

    const int xk   = (c & 7) << 3;
    const int vcol = (g * 8) ^ ((((c & 3) ^ ((c >> 2) & 3))) << 3);
    unsigned short* Pw = &Plds[w * 16 * PROW];

    for (int kt = ts; kt < te; ++kt) {
        __builtin_amdgcn_s_barrier();   // all waves done reading buf^1
        if (kt + 1 < te) {
            STAGE(kt + 1, buf ^ 1);
            asm volatile("s_waitcnt vmcnt(4)" ::: "memory");  // tile kt landed
        } else {
            asm volatile("s_waitcnt vmcnt(0)" ::: "memory");
        }
        __builtin_amdgcn_s_barrier();   // tile kt visible to all waves

        const unsigned short* Kl = &Klds[buf][0];
        const unsigned short* Vl = &Vlds[buf][0];

        // S = Q K^T
        f32x4 s0 = f32x4{0.f, 0.f, 0.f, 0.f};
        f32x4 s1 = f32x4{0.f, 0.f, 0.f, 0.f};
        __builtin_amdgcn_s_setprio(1);
        #pragma unroll
        for (int ks = 0; ks < 8; ++ks) {
            int off = (ks * 32 + g * 8) ^ xk;
            bf16x8 kf0 = *(const bf16x8*)&Kl[c * 256 + off];
            s0 = __builtin_amdgcn_mfma_f32_16x16x32_bf16(qf[ks], kf0, s0, 0, 0, 0);
            bf16x8 kf1 = *(const bf16x8*)&Kl[(16 + c) * 256 + off];
            s1 = __builtin_amdgcn_mfma_f32_16x16x32_bf16(qf[ks], kf1, s1, 0, 0, 0);
        }
        __builtin_amdgcn_s_setprio(0);

        // defer-max online softmax (no shuffles on the common path)
        float pm[4];
        #pragma unroll
        for (int j = 0; j < 4; ++j)
            pm[j] = fmaxf(s0[j], s1[j]) * sc_qk;
        bool ok = (pm[0] <= m[0] + 8.f) && (pm[1] <= m[1] + 8.f) &&
                  (pm[2] <= m[2] + 8.f) && (pm[3] <= m[3] + 8.f);
        if (!__all(ok)) {   // rare: first tile + occasional max growth
            float scj[4];
            #pragma unroll
            for (int j = 0; j < 4; ++j) {
                float pr = pm[j];
                for (int d = 1; d < 16; d <<= 1) pr = fmaxf(pr, __shfl_xor(pr, d));
                float mn = fmaxf(m[j], pr);
                float r  = __expf(m[j] - mn);
                m[j] = mn; llane[j] *= r; scj[j] = r;
            }
            #pragma unroll
            for (int nt = 0; nt < 16; ++nt) {
                o[nt][0] *= scj[0]; o[nt][1] *= scj[1];
                o[nt][2] *= scj[2]; o[nt][3] *= scj[3];
            }
        }
        #pragma unroll
        for (int j = 0; j < 4; ++j) {
            float p0 = __expf(s0[j] * sc_qk - m[j]);
            float p1 = __expf(s1[j] * sc_qk - m[j]);
            llane[j] += p0 + p1;
            int prow = g * 4 + j;
            Pw[prow * PROW + c]      = (unsigned short)f2bf(p0);
            Pw[prow * PROW + 16 + c] = (unsigned short)f2bf(p1);
        }

        // PV: O[16][256] += P[16][32] @ V[32][256]
        bf16x8 pa = *(const bf16x8*)&Pw[c * PROW + g * 8];
        __builtin_amdgcn_s_setprio(1);
        #pragma unroll
        for (int nt = 0; nt < 16; ++nt) {
            bf16x8 vf = *(const bf16x8*)&Vl[(nt * 16 + c) * 32 + vcol];
            o[nt] = __builtin_amdgcn_mfma_f32_16x16x32_bf16(pa, vf, o[nt], 0, 0, 0);
        }
        __builtin_amdgcn_s_setprio(0);
        buf ^= 1;
    }

    // epilogue: reduce l across the 16-lane row groups, normalize, store
    float lr[4];
    #pragma unroll
    for (int j = 0; j < 4; ++j) {
        float v = llane[j];
        for (int d = 1; d < 16; d <<= 1) v += __shfl_xor(v, d);
        lr[j] = v;
    }
    float inv[4];
    #pragma unroll
    for (int j = 0; j < 4; ++j) inv[j] = 1.0f / lr[j];
    const size_t obase = ((size_t)sidx * BATCH * SEQ + (size_t)b * SEQ + wrow) * DIM;
    for (int nt = 0; nt < 16; ++nt)
        for (int j = 0; j < 4; ++j)
            Opart[obase + (size_t)(g * 4 + j) * DIM + nt * 16 + c] = o[nt][j] * inv[j];
    if (c == 0) {
        for (int j = 0; j < 4; ++j)
            ml[(size_t)sidx * BATCH * SEQ + (size_t)b * SEQ + wrow + g * 4 + j] =
                make_float2(m[j], lr[j]);
    }
}

// ---------------------------------------------------------------------------
// Combine 4 KV-split partials: O = sum_s w_s * O_s, w_s = l_s exp(m_s - M)/L
// ---------------------------------------------------------------------------
__global__ __launch_bounds__(256) void combine_kernel(
    const float* __restrict__ Opart, const float2* __restrict__ ml,
    float* __restrict__ out)
{
    const int t = threadIdx.x;
    const size_t row = (size_t)blockIdx.x * 4 + (t >> 6);
    const int lane = t & 63;

    float2 e[4];
    float M = -1e30f;
    for (int s = 0; s < 4; ++s) {
        e[s] = ml[(size_t)s * BATCH * SEQ + row];
        M = fmaxf(M, e[s].x);
    }
    float wgt[4], L = 0.f;
    for (int s = 0; s < 4; ++s) { wgt[s] = e[s].y * __expf(e[s].x - M); L += wgt[s]; }
    float invL = 1.0f / L;

    f32x4 acc = f32x4{0.f, 0.f, 0.f, 0.f};
    for (int s = 0; s < 4; ++s) {
        f32x4 v = *(const f32x4*)&Opart[((size_t)s * BATCH * SEQ + row) * DIM + lane * 4];
        float ws = wgt[s] * invL;
        acc[0] += ws * v[0]; acc[1] += ws * v[1];
        acc[2] += ws * v[2]; acc[3] += ws * v[3];
    }
    *(f32x4*)&out[row * DIM + lane * 4] = acc;
}

// ---------------------------------------------------------------------------
extern "C" void kernel_launch(void* const* d_in, const int* in_sizes, int n_in,
                              void* d_out, int out_size, void* d_ws, size_t ws_size,
                              hipStream_t stream) {
    const float* x  = (const float*)d_in[0];
    const float* z  = (const float*)d_in[1];
    const float* Wq = (const float*)d_in[2];
    const float* bq = (const float*)d_in[3];
    const float* Wk = (const float*)d_in[4];
    const float* bk = (const float*)d_in[5];
    const float* Wv = (const float*)d_in[6];
    const float* bv = (const float*)d_in[7];
    float* out = (float*)d_out;

    const size_t TENS = (size_t)BATCH * SEQ * DIM;
    unsigned short* Qb  = (unsigned short*)d_ws;
    unsigned short* Kb  = Qb + TENS;
    unsigned short* Vtb = Kb + TENS;

    const size_t base_bytes = 3 * TENS * sizeof(unsigned short);       // 24 MB
    const size_t need4 = base_bytes + 4 * TENS * sizeof(float)         // 64 MB
                       + 4 * (size_t)BATCH * SEQ * sizeof(float2);
    const int nsplit = (ws_size >= need4) ? 4 : 1;

    proj_kernel<false><<<256, 256, 0, stream>>>(x, Wq, bq, Qb);
    proj_kernel<false><<<256, 256, 0, stream>>>(z, Wk, bk, Kb);
    proj_kernel<true ><<<256, 256, 0, stream>>>(z, Wv, bv, Vtb);

    if (nsplit == 4) {
        float*  Op  = (float*)((char*)d_ws + base_bytes);
        float2* mlb = (float2*)((char*)d_ws + base_bytes + 4 * TENS * sizeof(float));
        fa2_kernel<<<512, 512, 0, stream>>>(Qb, Kb, Vtb, Op, mlb, 4);
        combine_kernel<<<4096, 256, 0, stream>>>(Op, mlb, out);
    } else {
        float2* mlb = (float2*)((char*)d_ws + base_bytes);
        fa2_kernel<<<128, 512, 0, stream>>>(Qb, Kb, Vtb, out, mlb, 1);
    }
}